// Round 14
// baseline (5821.636 us; speedup 1.0000x reference)
//
#include <hip/hip_runtime.h>
#include <hip/hip_fp16.h>

#define BB 32
#define CC 512
#define UU 512
#define GG 1536
#define VV 1024
#define TT 512
#define MM (BB*TT)   // 16384
#define TIN 1024
#define FIN 80
#define EPS 1e-3f
#define SENT 0xFFFFFFFFu   // two f16 NaNs — impossible as finite GRU output

typedef _Float16 h8 __attribute__((ext_vector_type(8)));
typedef float f4 __attribute__((ext_vector_type(4)));

// ---------------- conv1d(stride2,SAME) + bias + relu + BN -> f16 ----------------
__global__ __launch_bounds__(256) void conv_bn_k(
    const float* __restrict__ x, const float* __restrict__ w, const float* __restrict__ cb,
    const float* __restrict__ gam, const float* __restrict__ bet,
    const float* __restrict__ mu_, const float* __restrict__ var_,
    __half* __restrict__ out)
{
  __shared__ float xs[41*80];
  int tg = blockIdx.x, b = blockIdx.y, ch = blockIdx.z;
  int t0 = tg*16;
  int in0 = t0*2 - 4;
  for (int i = threadIdx.x; i < 41*80; i += 256) {
    int r = i / 80, f = i - r*80;
    int ri = in0 + r;
    xs[i] = (ri >= 0 && ri < TIN) ? x[((size_t)b*TIN + ri)*FIN + f] : 0.f;
  }
  __syncthreads();
  int c = ch*256 + threadIdx.x;
  float acc[16];
  float bv = cb[c];
#pragma unroll
  for (int i = 0; i < 16; i++) acc[i] = bv;
  for (int k = 0; k < 11; k++) {
    for (int f = 0; f < 80; f++) {
      float wv = w[((size_t)k*80 + f)*CC + c];
#pragma unroll
      for (int i = 0; i < 16; i++) acc[i] += xs[(2*i + k)*80 + f] * wv;
    }
  }
  float ga = gam[c], be = bet[c], mu = mu_[c], iv = rsqrtf(var_[c] + EPS);
#pragma unroll
  for (int i = 0; i < 16; i++) {
    float v = fmaxf(acc[i], 0.f);
    out[((size_t)b*TT + t0 + i)*CC + c] = __float2half(ga*(v - mu)*iv + be);
  }
}

// -------- prep: transpose+cvt Wx (512x1536 f32) -> WxT2 (1536 x 1024 f16, k dup) --------
__global__ __launch_bounds__(256) void prep_wx_k(
    const float* __restrict__ wxf, const float* __restrict__ wxb,
    __half* __restrict__ of, __half* __restrict__ ob)
{
  __shared__ float tile[64][65];
  int kt = blockIdx.x*64, nt = blockIdx.y*64;
  const float* src = blockIdx.z ? wxb : wxf;
  __half* dst = blockIdx.z ? ob : of;
  for (int i = threadIdx.x; i < 4096; i += 256) {
    int r = i >> 6, c = i & 63;
    tile[r][c] = src[(size_t)(kt+r)*GG + nt + c];
  }
  __syncthreads();
  for (int i = threadIdx.x; i < 4096; i += 256) {
    int r = i >> 6, c = i & 63;          // r = n, c = k
    __half h = __float2half(tile[c][r]);
    dst[(size_t)(nt+r)*1024 + kt + c] = h;
    dst[(size_t)(nt+r)*1024 + 512 + kt + c] = h;
  }
}

// -------- prep: dense_w (512x1024) scaled by BN gamma*rsqrt -> DwT2 (1024x1024 f16, dup) --------
__global__ __launch_bounds__(256) void prep_dense_k(
    const float* __restrict__ dw, const float* __restrict__ gam, const float* __restrict__ var_,
    __half* __restrict__ dst)
{
  __shared__ float tile[64][65];
  __shared__ float s64[64];
  int kt = blockIdx.x*64, nt = blockIdx.y*64;
  if (threadIdx.x < 64) {
    int k = kt + threadIdx.x;
    s64[threadIdx.x] = gam[k] * rsqrtf(var_[k] + EPS);
  }
  for (int i = threadIdx.x; i < 4096; i += 256) {
    int r = i >> 6, c = i & 63;
    tile[r][c] = dw[(size_t)(kt+r)*VV + nt + c];
  }
  __syncthreads();
  for (int i = threadIdx.x; i < 4096; i += 256) {
    int r = i >> 6, c = i & 63;          // r = n, c = k
    __half h = __float2half(tile[c][r] * s64[c]);
    dst[(size_t)(nt+r)*1024 + kt + c] = h;
    dst[(size_t)(nt+r)*1024 + 512 + kt + c] = h;
  }
}

// -------- prep: bias2[n] = db[n] + sum_k (bet - gam*mu*rs)[k] * dw[k][n] --------
__global__ __launch_bounds__(256) void prep_bias_k(
    const float* __restrict__ dw, const float* __restrict__ db,
    const float* __restrict__ gam, const float* __restrict__ bet,
    const float* __restrict__ mu_, const float* __restrict__ var_,
    float* __restrict__ bias2)
{
  int n = blockIdx.x*256 + threadIdx.x;
  float acc = db[n];
  for (int k = 0; k < CC; k++) {
    float o = bet[k] - gam[k]*mu_[k]*rsqrtf(var_[k] + EPS);
    acc += o * dw[(size_t)k*VV + n];
  }
  bias2[n] = acc;
}

// ---------------- f16 MFMA GEMM (double-buffered), used for the layer-1 xg GEMMs --------
template<int OUTH>
__global__ __launch_bounds__(256,2) void hgemm_k(
    const __half* __restrict__ A, const __half* __restrict__ BT,
    const float* __restrict__ bias, void* __restrict__ Cout,
    int M, int N, int K, int lda, int ldb)
{
  __shared__ _Float16 As[2][128*40];
  __shared__ _Float16 Bs[2][128*40];
  int m0 = blockIdx.y*128, n0 = blockIdx.x*128;
  int tid = threadIdx.x;
  int l = tid & 63, w = tid >> 6;
  int wr = w >> 1, wc = w & 1;
  int srow = tid >> 1, soff = (tid & 1)*16;
  const __half* ap = A  + (size_t)(m0 + srow)*lda + soff;
  const __half* bp = BT + (size_t)(n0 + srow)*ldb + soff;
  f4 acc[4][4];
#pragma unroll
  for (int i=0;i<4;i++)
#pragma unroll
    for (int j=0;j<4;j++) acc[i][j] = (f4){0.f,0.f,0.f,0.f};

  uint4 av  = *(const uint4*)(ap);
  uint4 av2 = *(const uint4*)(ap + 8);
  uint4 bv  = *(const uint4*)(bp);
  uint4 bv2 = *(const uint4*)(bp + 8);
  *(uint4*)&As[0][srow*40 + soff]     = av;
  *(uint4*)&As[0][srow*40 + soff + 8] = av2;
  *(uint4*)&Bs[0][srow*40 + soff]     = bv;
  *(uint4*)&Bs[0][srow*40 + soff + 8] = bv2;
  __syncthreads();

  int lr = (l & 15), lk = (l >> 4)*8;
  int nk = K >> 5;
  for (int kt = 0; kt < nk; kt++) {
    int cb_ = kt & 1;
    if (kt + 1 < nk) {
      av  = *(const uint4*)(ap + kt*32 + 32);
      av2 = *(const uint4*)(ap + kt*32 + 40);
      bv  = *(const uint4*)(bp + kt*32 + 32);
      bv2 = *(const uint4*)(bp + kt*32 + 40);
    }
    h8 af[4], bf[4];
#pragma unroll
    for (int i = 0; i < 4; i++)
      af[i] = *(const h8*)&As[cb_][(wr*64 + i*16 + lr)*40 + lk];
#pragma unroll
    for (int j = 0; j < 4; j++)
      bf[j] = *(const h8*)&Bs[cb_][(wc*64 + j*16 + lr)*40 + lk];
#pragma unroll
    for (int i = 0; i < 4; i++)
#pragma unroll
      for (int j = 0; j < 4; j++)
        acc[i][j] = __builtin_amdgcn_mfma_f32_16x16x32_f16(af[i], bf[j], acc[i][j], 0, 0, 0);
    if (kt + 1 < nk) {
      *(uint4*)&As[cb_^1][srow*40 + soff]     = av;
      *(uint4*)&As[cb_^1][srow*40 + soff + 8] = av2;
      *(uint4*)&Bs[cb_^1][srow*40 + soff]     = bv;
      *(uint4*)&Bs[cb_^1][srow*40 + soff + 8] = bv2;
    }
    __syncthreads();
  }
  int cb = n0 + wc*64 + lr;
  int rb = m0 + wr*64 + (l >> 4)*4;
#pragma unroll
  for (int j = 0; j < 4; j++) {
    float bs = bias[cb + j*16];
#pragma unroll
    for (int i = 0; i < 4; i++) {
#pragma unroll
      for (int q = 0; q < 4; q++) {
        float v = acc[i][j][q] + bs;
        int row = rb + i*16 + q, col = cb + j*16;
        if (OUTH) ((__half*)Cout)[(size_t)row*N + col] = __float2half(v);
        else      ((float*)Cout)[(size_t)row*N + col] = v;
      }
    }
  }
}

// ---------------- worker tile: C[m0..+128, n0..+128] = H(sc0sc1)@BT + bias ----------------
// K = lda = ldb = 1024 fixed. Single-buffered LDS; A read device-coherent.
__device__ __forceinline__ void worker_tile(
    const unsigned short* __restrict__ Hh, const __half* __restrict__ BT,
    const float* __restrict__ bias, void* __restrict__ Cout,
    int m0, int n0, int N, int OUTH,
    _Float16* As, _Float16* Bs, int tid)
{
  int l = tid & 63, w = tid >> 6;
  int wr = w >> 1, wc = w & 1;
  int srow = tid >> 1, soff = (tid & 1)*16;
  const __half* bp = BT + (size_t)(n0 + srow)*1024 + soff;
  const unsigned short* apB = Hh + (size_t)(m0 + srow)*1024 + soff;
  f4 acc[4][4];
#pragma unroll
  for (int i=0;i<4;i++)
#pragma unroll
    for (int j=0;j<4;j++) acc[i][j] = (f4){0.f,0.f,0.f,0.f};
  int lr = (l & 15), lk = (l >> 4)*8;
  for (int kt = 0; kt < 32; kt++) {
    uint4 a0, a1;
    const unsigned short* gpa = apB + kt*32;
    asm volatile(
      "global_load_dwordx4 %0, %2, off sc0 sc1\n\t"
      "global_load_dwordx4 %1, %2, off offset:16 sc0 sc1\n\t"
      "s_waitcnt vmcnt(0)"
      : "=&v"(a0), "=&v"(a1) : "v"(gpa) : "memory");
    uint4 b0 = *(const uint4*)(bp + kt*32);
    uint4 b1 = *(const uint4*)(bp + kt*32 + 8);
    __syncthreads();
    *(uint4*)&As[srow*40 + soff]     = a0;
    *(uint4*)&As[srow*40 + soff + 8] = a1;
    *(uint4*)&Bs[srow*40 + soff]     = b0;
    *(uint4*)&Bs[srow*40 + soff + 8] = b1;
    __syncthreads();
    h8 af[4], bf[4];
#pragma unroll
    for (int i = 0; i < 4; i++)
      af[i] = *(const h8*)&As[(wr*64 + i*16 + lr)*40 + lk];
#pragma unroll
    for (int j = 0; j < 4; j++)
      bf[j] = *(const h8*)&Bs[(wc*64 + j*16 + lr)*40 + lk];
#pragma unroll
    for (int i = 0; i < 4; i++)
#pragma unroll
      for (int j = 0; j < 4; j++)
        acc[i][j] = __builtin_amdgcn_mfma_f32_16x16x32_f16(af[i], bf[j], acc[i][j], 0, 0, 0);
  }
  int cb = n0 + wc*64 + lr;
  int rb = m0 + wr*64 + (l >> 4)*4;
#pragma unroll
  for (int j = 0; j < 4; j++) {
    float bs = bias[cb + j*16];
#pragma unroll
    for (int i = 0; i < 4; i++) {
#pragma unroll
      for (int q = 0; q < 4; q++) {
        float v = acc[i][j][q] + bs;
        int row = rb + i*16 + q, col = cb + j*16;
        if (OUTH) ((__half*)Cout)[(size_t)row*N + col] = __float2half(v);
        else      ((float*)Cout)[(size_t)row*N + col] = v;
      }
    }
  }
}

// ---------------- fused persistent GRU layer + progressive consumer GEMM ---------
// Grid 256: blocks 0-63 run the (unchanged R13) recurrence and publish per-WG
// progress flags; blocks 64-255 (plus finished gru blocks) pull 128x128 tiles
// of the H-consuming GEMM from an atomic queue, gated on the flags.
// L==1: consumes H1 -> xg2 (written IN PLACE over xg1: flag semantics prove the
//       overwritten rows are already consumed+prefetched by the gru).
// L==2: consumes H2 -> logits (dense, fp32 out).
// Flag semantics: flag[dir*32+bg*8+wg] = n  <=>  that WG's first n steps are
// fully drained to L3 (H u64-atomic stores execute at the coherence point; the
// end-of-step __syncthreads drains vmcnt before the flag for step n is posted).
// Tile (b, t in [tlo,thi)) ready iff min fwd flags(bg) >= thi and
// min bwd flags(bg) >= 512-tlo.
template<int L>
__global__ __launch_bounds__(256,1) void gru_fused_k(
    const __half* __restrict__ xgf, const __half* __restrict__ xgb,
    const float* __restrict__ whf, const float* __restrict__ whb,
    const float* __restrict__ brf, const float* __restrict__ brb,
    __half* __restrict__ H,           // [16384][1024], cols dir*512+u
    unsigned* __restrict__ hbL,       // [8 grp][4 phase][8 wg][256 u32]
    const __half* __restrict__ BTa, const __half* __restrict__ BTb,
    const float* __restrict__ bsa, const float* __restrict__ bsb,
    void* __restrict__ outA, void* __restrict__ outB,
    unsigned* __restrict__ flags, unsigned* __restrict__ queue)
{
  int tid = threadIdx.x;
  __shared__ _Float16 hsl[2][8][544];   // gru staging
  __shared__ _Float16 As[128*40];       // worker tiles
  __shared__ _Float16 Bs[128*40];
  __shared__ unsigned tileS;

  if (blockIdx.x < 64) {
    // ================= recurrence (R13 schedule, + flags, atomic H) =================
    int wg  = blockIdx.x & 7;
    int bg  = (blockIdx.x >> 3) & 3;
    int dir = blockIdx.x >> 5;
    int grp = dir*4 + bg;
    const __half* xg = dir ? xgb : xgf;
    const float* wh  = dir ? whb : whf;
    const float* brc = dir ? brb : brf;
    unsigned* hbg = hbL + (size_t)grp*8192;
    unsigned* myflag = flags + dir*32 + bg*8 + wg;
    int L_ = tid & 63, wv = tid >> 6;
    int u0 = wg*64, b0 = bg*8;

    int urow = L_ & 15, kb = L_ >> 4;
    int ubase = u0 + wv*16;
    h8 wb[3][16];
#pragma unroll
    for (int g3 = 0; g3 < 3; g3++)
#pragma unroll
      for (int ks = 0; ks < 16; ks++) {
        h8 v;
#pragma unroll
        for (int j = 0; j < 8; j++)
          v[j] = (_Float16)wh[(size_t)(ks*32 + kb*8 + j)*GG + g3*512 + ubase + urow];
        wb[g3][ks] = v;
      }

    int b = L_ & 15, b7 = L_ & 7;
    int myu = ubase + kb*4;
    float br3[3][4];
#pragma unroll
    for (int g3 = 0; g3 < 3; g3++)
#pragma unroll
      for (int q = 0; q < 4; q++)
        br3[g3][q] = brc[g3*512 + myu + q];
    float hreg[4] = {0.f, 0.f, 0.f, 0.f};
    bool bval = b < 8;
    int upair = (u0 >> 1) + wv*8 + kb*2;

    uint2 xz2, xr2, xh2;
    {
      int t0_ = dir ? 511 : 0;
      const unsigned* xp = (const unsigned*)xg + (size_t)((b0 + b7)*TT + t0_)*768;
      xz2 = *(const uint2*)(xp + upair);
      xr2 = *(const uint2*)(xp + 256 + upair);
      xh2 = *(const uint2*)(xp + 512 + upair);
    }

    (void)__hip_atomic_exchange(&hbg[0*2048 + wg*256 + tid], 0u,
                                __ATOMIC_RELAXED, __HIP_MEMORY_SCOPE_AGENT);

    int sr = tid >> 5, sc = tid & 31;
    int sb = sc >> 2, sg0 = sr*8 + (sc & 3)*2;
    int sws0 = ((sg0 ^ sb) << 3), sws1 = (((sg0 + 1) ^ sb) << 3);

#define STAGE(PH, NB) {                                                     \
    const unsigned* gp = &hbg[(PH)*2048 + sr*256 + sc*8];                   \
    uint4 d0, d1;                                                           \
    long guard = 0;                                                         \
    for (;;) {                                                              \
      asm volatile(                                                         \
        "global_load_dwordx4 %0, %2, off sc0 sc1\n\t"                       \
        "global_load_dwordx4 %1, %2, off offset:16 sc0 sc1\n\t"             \
        "s_waitcnt vmcnt(0)"                                                \
        : "=&v"(d0), "=&v"(d1) : "v"(gp) : "memory");                       \
      bool ok = (d0.x!=SENT)&(d0.y!=SENT)&(d0.z!=SENT)&(d0.w!=SENT)         \
              & (d1.x!=SENT)&(d1.y!=SENT)&(d1.z!=SENT)&(d1.w!=SENT);        \
      if (ok || ++guard > 2000000L) break;                                  \
      if (guard > 2) __builtin_amdgcn_s_sleep(1);                           \
    }                                                                       \
    *(uint4*)&hsl[NB][sb][sws0] = d0;                                       \
    *(uint4*)&hsl[NB][sb][sws1] = d1;                                       \
  }

    STAGE(0, 0);
    __syncthreads();

    for (int s = 0; s < 512; s++) {
      int buf = s & 1;
      if (tid == 0)
        __hip_atomic_store(myflag, (unsigned)s,
                           __ATOMIC_RELAXED, __HIP_MEMORY_SCOPE_AGENT);
      f4 a0 = (f4){0.f,0.f,0.f,0.f}, a1 = a0, a2 = a0;
#pragma unroll
      for (int ks = 0; ks < 16; ks++) {
        int g = ks*4 + kb;
        h8 hf = *(const h8*)&hsl[buf][b7][(g ^ b7) << 3];
        a0 = __builtin_amdgcn_mfma_f32_16x16x32_f16(wb[0][ks], hf, a0, 0, 0, 0);
        a1 = __builtin_amdgcn_mfma_f32_16x16x32_f16(wb[1][ks], hf, a1, 0, 0, 0);
        a2 = __builtin_amdgcn_mfma_f32_16x16x32_f16(wb[2][ks], hf, a2, 0, 0, 0);
      }
      int t = dir ? (511 - s) : s;
      __half2 xzl = *(__half2*)&xz2.x, xzh = *(__half2*)&xz2.y;
      __half2 xrl = *(__half2*)&xr2.x, xrh = *(__half2*)&xr2.y;
      __half2 xhl = *(__half2*)&xh2.x, xhh = *(__half2*)&xh2.y;
      float2 fz0 = __half22float2(xzl), fz1 = __half22float2(xzh);
      float2 fr0 = __half22float2(xrl), fr1 = __half22float2(xrh);
      float2 fh0 = __half22float2(xhl), fh1 = __half22float2(xhh);
      float xzf[4] = {fz0.x, fz0.y, fz1.x, fz1.y};
      float xrf[4] = {fr0.x, fr0.y, fr1.x, fr1.y};
      float xhf[4] = {fh0.x, fh0.y, fh1.x, fh1.y};
#pragma unroll
      for (int q = 0; q < 4; q++) {
        float az = (q==0? a0[0] : q==1? a0[1] : q==2? a0[2] : a0[3]);
        float ar = (q==0? a1[0] : q==1? a1[1] : q==2? a1[2] : a1[3]);
        float ah = (q==0? a2[0] : q==1? a2[1] : q==2? a2[2] : a2[3]);
        float z = 1.f/(1.f + __expf(-(xzf[q] + br3[0][q] + az)));
        float r = 1.f/(1.f + __expf(-(xrf[q] + br3[1][q] + ar)));
        float hh = fmaxf(xhf[q] + r*(br3[2][q] + ah), 0.f);
        hreg[q] = z*hreg[q] + (1.f - z)*hh;
      }
      int pn = (s + 1) & 3;
      if (bval) {
        __half2 p01 = __floats2half2_rn(hreg[0], hreg[1]);
        __half2 p23 = __floats2half2_rn(hreg[2], hreg[3]);
        unsigned pk0 = *(unsigned*)&p01, pk1 = *(unsigned*)&p23;
        unsigned long long pkl = ((unsigned long long)pk1 << 32) | pk0;
        (void)__hip_atomic_exchange(
            (unsigned long long*)&hbg[pn*2048 + wg*256 + b*32 + wv*8 + kb*2],
            pkl, __ATOMIC_RELAXED, __HIP_MEMORY_SCOPE_AGENT);
        // H sequence output: u64 atomic store -> executes (and lands) at L3,
        // so the flag protocol can certify it to consumer tiles.
        __hip_atomic_store(
            (unsigned long long*)((unsigned*)H + (size_t)((b0 + b)*TT + t)*512
                                  + dir*256 + upair),
            pkl, __ATOMIC_RELAXED, __HIP_MEMORY_SCOPE_AGENT);
      }
      {
        int tn = (dir ? (510 - s) : (s + 1)) & 511;
        const unsigned* xp = (const unsigned*)xg + (size_t)((b0 + b7)*TT + tn)*768;
        xz2 = *(const uint2*)(xp + upair);
        xr2 = *(const uint2*)(xp + 256 + upair);
        xh2 = *(const uint2*)(xp + 512 + upair);
      }
      if (s < 511) STAGE(pn, buf ^ 1);
      if (tid < 128)
        (void)__hip_atomic_exchange(
            (unsigned long long*)&hbg[((s+3)&3)*2048 + wg*256] + tid,
            0xFFFFFFFFFFFFFFFFull, __ATOMIC_RELAXED, __HIP_MEMORY_SCOPE_AGENT);
      __syncthreads();   // vmcnt drain: H stores + publishes of step s at L3
    }
#undef STAGE
    if (tid == 0)
      __hip_atomic_store(myflag, 512u, __ATOMIC_RELAXED, __HIP_MEMORY_SCOPE_AGENT);
    // fall through: join the worker pool for the GEMM tail
  }

  // ================= worker: progressive H-consuming GEMM =================
  const int NT = (L == 1) ? 3072 : 1024;
  for (;;) {
    __syncthreads();
    if (tid == 0)
      tileS = __hip_atomic_fetch_add(queue, 1u, __ATOMIC_RELAXED,
                                     __HIP_MEMORY_SCOPE_AGENT);
    __syncthreads();
    unsigned tv = tileS;
    if (tv >= (unsigned)NT) break;
    int b, tb, nt, g;
    if (L == 1) {
      int half = tv >= 1536; int i = half ? (int)tv - 1536 : (int)tv;
      g = i & 1; i >>= 1; nt = i % 12; int bm = i / 12;
      b = bm >> 1; tb = half ? ((bm & 1) ? 3 : 0) : (1 + (bm & 1));
    } else {
      int half = tv >= 512; int i = half ? (int)tv - 512 : (int)tv;
      g = 0; nt = i & 7; int bm = i >> 3;
      b = bm >> 1; tb = half ? ((bm & 1) ? 3 : 0) : (1 + (bm & 1));
    }
    int tlo = tb*128, thi = tlo + 128;
    int bgx = b >> 3;
    if (tid == 0) {
      const unsigned* ff = flags + bgx*8;        // fwd flags
      const unsigned* fb = flags + 32 + bgx*8;   // bwd flags
      long guard = 0;
      for (;;) {
        unsigned mf = 0xFFFFFFFFu, mb = 0xFFFFFFFFu;
#pragma unroll
        for (int i2 = 0; i2 < 8; i2++) {
          unsigned a = __hip_atomic_load(ff + i2, __ATOMIC_RELAXED,
                                         __HIP_MEMORY_SCOPE_AGENT);
          unsigned c = __hip_atomic_load(fb + i2, __ATOMIC_RELAXED,
                                         __HIP_MEMORY_SCOPE_AGENT);
          mf = a < mf ? a : mf; mb = c < mb ? c : mb;
        }
        if (mf >= (unsigned)thi && mb >= (unsigned)(512 - tlo)) break;
        if (++guard > 30000000L) break;   // bail: wrong answer, no hang
        __builtin_amdgcn_s_sleep(16);
      }
    }
    __syncthreads();
    int m0 = (b*4 + tb) * 128;   // = b*512 + tlo
    int n0 = nt * 128;
    if (L == 1)
      worker_tile((const unsigned short*)H, g ? BTb : BTa, g ? bsb : bsa,
                  g ? outB : outA, m0, n0, GG, 1, As, Bs, tid);
    else
      worker_tile((const unsigned short*)H, BTa, bsa, outA, m0, n0, VV, 0,
                  As, Bs, tid);
  }
}

// ---------------- row softmax over V=1024, in place ----------------
__global__ __launch_bounds__(256) void softmax_k(float* __restrict__ p) {
  size_t row = blockIdx.x;
  float* pr = p + row*VV;
  int tid = threadIdx.x;
  float4 v = ((float4*)pr)[tid];
  float m = fmaxf(fmaxf(v.x, v.y), fmaxf(v.z, v.w));
#pragma unroll
  for (int o = 32; o >= 1; o >>= 1) m = fmaxf(m, __shfl_xor(m, o));
  __shared__ float red[4];
  __shared__ float red2[4];
  int w = tid >> 6;
  if ((tid & 63) == 0) red[w] = m;
  __syncthreads();
  m = fmaxf(fmaxf(red[0], red[1]), fmaxf(red[2], red[3]));
  v.x = __expf(v.x - m); v.y = __expf(v.y - m);
  v.z = __expf(v.z - m); v.w = __expf(v.w - m);
  float s = v.x + v.y + v.z + v.w;
#pragma unroll
  for (int o = 32; o >= 1; o >>= 1) s += __shfl_xor(s, o);
  if ((tid & 63) == 0) red2[w] = s;
  __syncthreads();
  s = red2[0] + red2[1] + red2[2] + red2[3];
  float inv = 1.f / s;
  v.x *= inv; v.y *= inv; v.z *= inv; v.w *= inv;
  ((float4*)pr)[tid] = v;
}

extern "C" void kernel_launch(void* const* d_in, const int* in_sizes, int n_in,
                              void* d_out, int out_size, void* d_ws, size_t ws_size,
                              hipStream_t stream) {
  const float* x      = (const float*)d_in[0];
  const float* conv_w = (const float*)d_in[1];
  const float* conv_b = (const float*)d_in[2];
  const float* wx_f   = (const float*)d_in[3];
  const float* wh_f   = (const float*)d_in[4];
  const float* bi_f   = (const float*)d_in[5];
  const float* br_f   = (const float*)d_in[6];
  const float* wx_b   = (const float*)d_in[7];
  const float* wh_b   = (const float*)d_in[8];
  const float* bi_b   = (const float*)d_in[9];
  const float* br_b   = (const float*)d_in[10];
  const float* gam    = (const float*)d_in[11];
  const float* bet    = (const float*)d_in[12];
  const float* mu_    = (const float*)d_in[13];
  const float* var_   = (const float*)d_in[14];
  const float* dw     = (const float*)d_in[15];
  const float* db     = (const float*)d_in[16];

  char* ws = (char*)d_ws;
  __half* xgf   = (__half*)(ws + 0);
  __half* xgb   = (__half*)(ws + 50331648LL);
  __half* WxfT2 = (__half*)(ws + 100663296LL);
  __half* WxbT2 = (__half*)(ws + 103809024LL);
  __half* DwT2  = (__half*)(ws + 106954752LL);
  float*  bias2 = (float*)(ws + 109051904LL);
  __half* c0    = (__half*)(ws + 109056000LL);
  __half* H     = (__half*)(ws + 109056000LL);   // overlays c0 (c0 dead before H written)
  unsigned* hb1 = (unsigned*)(ws + 142610432LL); // 256 KB (layer 1 exchange)
  unsigned* hb2 = (unsigned*)(ws + 142872576LL); // 256 KB (layer 2 exchange)
  unsigned* fl1 = (unsigned*)(ws + 143134720LL); // 256 B  (layer 1 flags, 64 u32)
  unsigned* fl2 = (unsigned*)(ws + 143134976LL); // 256 B  (layer 2 flags)
  unsigned* q1  = (unsigned*)(ws + 143135232LL); // 64 B
  unsigned* q2  = (unsigned*)(ws + 143135296LL); // 64 B
  if (ws_size < 143135360ULL) return;
  float* logits = (float*)d_out;

  // sentinel-fill exchange buffers; zero flags + queues
  (void)hipMemsetAsync(hb1, 0xFF, 524288, stream);
  (void)hipMemsetAsync(fl1, 0, 640, stream);

  prep_wx_k<<<dim3(8,24,2), 256, 0, stream>>>(wx_f, wx_b, WxfT2, WxbT2);
  prep_dense_k<<<dim3(8,16), 256, 0, stream>>>(dw, gam, var_, DwT2);
  prep_bias_k<<<4, 256, 0, stream>>>(dw, db, gam, bet, mu_, var_, bias2);

  conv_bn_k<<<dim3(32,32,2), 256, 0, stream>>>(x, conv_w, conv_b, gam, bet, mu_, var_, c0);

  hgemm_k<1><<<dim3(12,128), 256, 0, stream>>>(c0, WxfT2, bi_f, xgf, MM, GG, 512, 512, 1024);
  hgemm_k<1><<<dim3(12,128), 256, 0, stream>>>(c0, WxbT2, bi_b, xgb, MM, GG, 512, 512, 1024);
  // layer 1: recurrence + progressive xg2 GEMM (in place over xg1)
  gru_fused_k<1><<<256, 256, 0, stream>>>(xgf, xgb, wh_f, wh_b, br_f, br_b,
                                          H, hb1, WxfT2, WxbT2, bi_f, bi_b,
                                          xgf, xgb, fl1, q1);
  // layer 2: recurrence + progressive dense GEMM -> logits
  gru_fused_k<2><<<256, 256, 0, stream>>>(xgf, xgb, wh_f, wh_b, br_f, br_b,
                                          H, hb2, DwT2, nullptr, bias2, nullptr,
                                          logits, nullptr, fl2, q2);
  softmax_k<<<MM, 256, 0, stream>>>(logits);
}

// Round 15
// 2787.262 us; speedup vs baseline: 2.0887x; 2.0887x over previous
//
#include <hip/hip_runtime.h>
#include <hip/hip_fp16.h>

#define BB 32
#define CC 512
#define UU 512
#define GG 1536
#define VV 1024
#define TT 512
#define MM (BB*TT)   // 16384
#define TIN 1024
#define FIN 80
#define EPS 1e-3f
#define SENT 0xFFFFFFFFu   // two f16 NaNs — impossible as finite GRU output

typedef _Float16 h8 __attribute__((ext_vector_type(8)));
typedef float f4 __attribute__((ext_vector_type(4)));

// ---------------- conv1d(stride2,SAME) + bias + relu + BN -> f16 ----------------
__global__ __launch_bounds__(256) void conv_bn_k(
    const float* __restrict__ x, const float* __restrict__ w, const float* __restrict__ cb,
    const float* __restrict__ gam, const float* __restrict__ bet,
    const float* __restrict__ mu_, const float* __restrict__ var_,
    __half* __restrict__ out)
{
  __shared__ float xs[41*80];
  int tg = blockIdx.x, b = blockIdx.y, ch = blockIdx.z;
  int t0 = tg*16;
  int in0 = t0*2 - 4;
  for (int i = threadIdx.x; i < 41*80; i += 256) {
    int r = i / 80, f = i - r*80;
    int ri = in0 + r;
    xs[i] = (ri >= 0 && ri < TIN) ? x[((size_t)b*TIN + ri)*FIN + f] : 0.f;
  }
  __syncthreads();
  int c = ch*256 + threadIdx.x;
  float acc[16];
  float bv = cb[c];
#pragma unroll
  for (int i = 0; i < 16; i++) acc[i] = bv;
  for (int k = 0; k < 11; k++) {
    for (int f = 0; f < 80; f++) {
      float wv = w[((size_t)k*80 + f)*CC + c];
#pragma unroll
      for (int i = 0; i < 16; i++) acc[i] += xs[(2*i + k)*80 + f] * wv;
    }
  }
  float ga = gam[c], be = bet[c], mu = mu_[c], iv = rsqrtf(var_[c] + EPS);
#pragma unroll
  for (int i = 0; i < 16; i++) {
    float v = fmaxf(acc[i], 0.f);
    out[((size_t)b*TT + t0 + i)*CC + c] = __float2half(ga*(v - mu)*iv + be);
  }
}

// -------- prep: transpose+cvt Wx (512x1536 f32) -> WxT2 (1536 x 1024 f16, k dup) --------
__global__ __launch_bounds__(256) void prep_wx_k(
    const float* __restrict__ wxf, const float* __restrict__ wxb,
    __half* __restrict__ of, __half* __restrict__ ob)
{
  __shared__ float tile[64][65];
  int kt = blockIdx.x*64, nt = blockIdx.y*64;
  const float* src = blockIdx.z ? wxb : wxf;
  __half* dst = blockIdx.z ? ob : of;
  for (int i = threadIdx.x; i < 4096; i += 256) {
    int r = i >> 6, c = i & 63;
    tile[r][c] = src[(size_t)(kt+r)*GG + nt + c];
  }
  __syncthreads();
  for (int i = threadIdx.x; i < 4096; i += 256) {
    int r = i >> 6, c = i & 63;          // r = n, c = k
    __half h = __float2half(tile[c][r]);
    dst[(size_t)(nt+r)*1024 + kt + c] = h;
    dst[(size_t)(nt+r)*1024 + 512 + kt + c] = h;
  }
}

// -------- prep: dense_w (512x1024) scaled by BN gamma*rsqrt -> DwT2 (1024x1024 f16, dup) --------
__global__ __launch_bounds__(256) void prep_dense_k(
    const float* __restrict__ dw, const float* __restrict__ gam, const float* __restrict__ var_,
    __half* __restrict__ dst)
{
  __shared__ float tile[64][65];
  __shared__ float s64[64];
  int kt = blockIdx.x*64, nt = blockIdx.y*64;
  if (threadIdx.x < 64) {
    int k = kt + threadIdx.x;
    s64[threadIdx.x] = gam[k] * rsqrtf(var_[k] + EPS);
  }
  for (int i = threadIdx.x; i < 4096; i += 256) {
    int r = i >> 6, c = i & 63;
    tile[r][c] = dw[(size_t)(kt+r)*VV + nt + c];
  }
  __syncthreads();
  for (int i = threadIdx.x; i < 4096; i += 256) {
    int r = i >> 6, c = i & 63;          // r = n, c = k
    __half h = __float2half(tile[c][r] * s64[c]);
    dst[(size_t)(nt+r)*1024 + kt + c] = h;
    dst[(size_t)(nt+r)*1024 + 512 + kt + c] = h;
  }
}

// -------- prep: bias2[n] = db[n] + sum_k (bet - gam*mu*rs)[k] * dw[k][n] --------
__global__ __launch_bounds__(256) void prep_bias_k(
    const float* __restrict__ dw, const float* __restrict__ db,
    const float* __restrict__ gam, const float* __restrict__ bet,
    const float* __restrict__ mu_, const float* __restrict__ var_,
    float* __restrict__ bias2)
{
  int n = blockIdx.x*256 + threadIdx.x;
  float acc = db[n];
  for (int k = 0; k < CC; k++) {
    float o = bet[k] - gam[k]*mu_[k]*rsqrtf(var_[k] + EPS);
    acc += o * dw[(size_t)k*VV + n];
  }
  bias2[n] = acc;
}

// ---------------- f16 MFMA GEMM, dual-output (g selects BT/bias/out) ----------------
// C_g[M,Ng] = A[M,K](f16,lda) @ BTg[Ng,K]^T(f16, ldb=1024) + bias_g.
// Grid x = 2*(Ng/128); g = x >= Ng/128. Double-buffered LDS, 1 barrier/K-step.
template<int OUTH>
__global__ __launch_bounds__(256,2) void hgemm2_k(
    const __half* __restrict__ A,
    const __half* __restrict__ BT0, const __half* __restrict__ BT1,
    const float* __restrict__ bs0, const float* __restrict__ bs1,
    void* __restrict__ out0, void* __restrict__ out1,
    int M, int Ng, int K, int lda)
{
  int ntile = Ng >> 7;
  int g = blockIdx.x >= ntile;
  const __half* BT = g ? BT1 : BT0;
  const float* bias = g ? bs1 : bs0;
  void* Cout = g ? out1 : out0;
  int n0 = (blockIdx.x - (g ? ntile : 0)) * 128;
  int m0 = blockIdx.y*128;

  __shared__ _Float16 As[2][128*40];
  __shared__ _Float16 Bs[2][128*40];
  int tid = threadIdx.x;
  int l = tid & 63, w = tid >> 6;
  int wr = w >> 1, wc = w & 1;
  int srow = tid >> 1, soff = (tid & 1)*16;
  const __half* ap = A  + (size_t)(m0 + srow)*lda + soff;
  const __half* bp = BT + (size_t)(n0 + srow)*1024 + soff;
  f4 acc[4][4];
#pragma unroll
  for (int i=0;i<4;i++)
#pragma unroll
    for (int j=0;j<4;j++) acc[i][j] = (f4){0.f,0.f,0.f,0.f};

  uint4 av  = *(const uint4*)(ap);
  uint4 av2 = *(const uint4*)(ap + 8);
  uint4 bv  = *(const uint4*)(bp);
  uint4 bv2 = *(const uint4*)(bp + 8);
  *(uint4*)&As[0][srow*40 + soff]     = av;
  *(uint4*)&As[0][srow*40 + soff + 8] = av2;
  *(uint4*)&Bs[0][srow*40 + soff]     = bv;
  *(uint4*)&Bs[0][srow*40 + soff + 8] = bv2;
  __syncthreads();

  int lr = (l & 15), lk = (l >> 4)*8;
  int nk = K >> 5;
  for (int kt = 0; kt < nk; kt++) {
    int cb_ = kt & 1;
    if (kt + 1 < nk) {
      av  = *(const uint4*)(ap + kt*32 + 32);
      av2 = *(const uint4*)(ap + kt*32 + 40);
      bv  = *(const uint4*)(bp + kt*32 + 32);
      bv2 = *(const uint4*)(bp + kt*32 + 40);
    }
    h8 af[4], bf[4];
#pragma unroll
    for (int i = 0; i < 4; i++)
      af[i] = *(const h8*)&As[cb_][(wr*64 + i*16 + lr)*40 + lk];
#pragma unroll
    for (int j = 0; j < 4; j++)
      bf[j] = *(const h8*)&Bs[cb_][(wc*64 + j*16 + lr)*40 + lk];
#pragma unroll
    for (int i = 0; i < 4; i++)
#pragma unroll
      for (int j = 0; j < 4; j++)
        acc[i][j] = __builtin_amdgcn_mfma_f32_16x16x32_f16(af[i], bf[j], acc[i][j], 0, 0, 0);
    if (kt + 1 < nk) {
      *(uint4*)&As[cb_^1][srow*40 + soff]     = av;
      *(uint4*)&As[cb_^1][srow*40 + soff + 8] = av2;
      *(uint4*)&Bs[cb_^1][srow*40 + soff]     = bv;
      *(uint4*)&Bs[cb_^1][srow*40 + soff + 8] = bv2;
    }
    __syncthreads();
  }
  int cb = n0 + wc*64 + lr;
  int rb = m0 + wr*64 + (l >> 4)*4;
#pragma unroll
  for (int j = 0; j < 4; j++) {
    float bs = bias[cb + j*16];
#pragma unroll
    for (int i = 0; i < 4; i++) {
#pragma unroll
      for (int q = 0; q < 4; q++) {
        float v = acc[i][j][q] + bs;
        int row = rb + i*16 + q, col = cb + j*16;
        if (OUTH) ((__half*)Cout)[(size_t)row*Ng + col] = __float2half(v);
        else      ((float*)Cout)[(size_t)row*Ng + col] = v;
      }
    }
  }
}

// ---------------- persistent bidirectional GRU layer (R13, best known) -----------
// 64 WGs = 2 dir x 4 batch-groups x 8 WGs. WG owns 64 u (wave owns 16 u).
// Swapped MFMA: A = Wh^T (regs), B = h^T (LDS). Gates fully lane-local.
// 4-phase sentinel regions; publish/reset via relaxed agent atomics; poll =
// sc0sc1 data loads (single hop) with s_sleep backoff after 2 fails.
__global__ __launch_bounds__(256,1) void gru_layer_k(
    const __half* __restrict__ xgf, const __half* __restrict__ xgb,
    const float* __restrict__ whf, const float* __restrict__ whb,
    const float* __restrict__ brf, const float* __restrict__ brb,
    __half* __restrict__ H,           // [16384][1024], cols dir*512+u
    unsigned* __restrict__ hbL)       // [8 grp][4 phase][8 wg][256 u32]
{
  int wg  = blockIdx.x & 7;
  int bg  = (blockIdx.x >> 3) & 3;
  int dir = blockIdx.x >> 5;
  int grp = dir*4 + bg;
  const __half* xg = dir ? xgb : xgf;
  const float* wh  = dir ? whb : whf;
  const float* brc = dir ? brb : brf;
  unsigned* hbg = hbL + (size_t)grp*8192;   // 4*8*256 u32 = 32KB per group
  int tid = threadIdx.x;
  int L = tid & 63, wv = tid >> 6;
  int u0 = wg*64, b0 = bg*8;

  __shared__ _Float16 hsl[2][8][544];   // [buf][batch][u+pad], swizzle g^b

  int urow = L & 15, kb = L >> 4;
  int ubase = u0 + wv*16;
  h8 wb[3][16];
#pragma unroll
  for (int g3 = 0; g3 < 3; g3++)
#pragma unroll
    for (int ks = 0; ks < 16; ks++) {
      h8 v;
#pragma unroll
      for (int j = 0; j < 8; j++)
        v[j] = (_Float16)wh[(size_t)(ks*32 + kb*8 + j)*GG + g3*512 + ubase + urow];
      wb[g3][ks] = v;
    }

  int b = L & 15, b7 = L & 7;
  int myu = ubase + kb*4;
  float br3[3][4];
#pragma unroll
  for (int g3 = 0; g3 < 3; g3++)
#pragma unroll
    for (int q = 0; q < 4; q++)
      br3[g3][q] = brc[g3*512 + myu + q];
  float hreg[4] = {0.f, 0.f, 0.f, 0.f};
  bool bval = b < 8;
  int upair = (u0 >> 1) + wv*8 + kb*2;

  uint2 xz2, xr2, xh2;
  {
    int t0_ = dir ? 511 : 0;
    const unsigned* xp = (const unsigned*)xg + (size_t)((b0 + b7)*TT + t0_)*768;
    xz2 = *(const uint2*)(xp + upair);
    xr2 = *(const uint2*)(xp + 256 + upair);
    xh2 = *(const uint2*)(xp + 512 + upair);
  }

  (void)__hip_atomic_exchange(&hbg[0*2048 + wg*256 + tid], 0u,
                              __ATOMIC_RELAXED, __HIP_MEMORY_SCOPE_AGENT);

  int sr = tid >> 5, sc = tid & 31;
  int sb = sc >> 2, sg0 = sr*8 + (sc & 3)*2;
  int sws0 = ((sg0 ^ sb) << 3), sws1 = (((sg0 + 1) ^ sb) << 3);

#define STAGE(PH, NB) {                                                     \
    const unsigned* gp = &hbg[(PH)*2048 + sr*256 + sc*8];                   \
    uint4 d0, d1;                                                           \
    long guard = 0;                                                         \
    for (;;) {                                                              \
      asm volatile(                                                         \
        "global_load_dwordx4 %0, %2, off sc0 sc1\n\t"                       \
        "global_load_dwordx4 %1, %2, off offset:16 sc0 sc1\n\t"             \
        "s_waitcnt vmcnt(0)"                                                \
        : "=&v"(d0), "=&v"(d1) : "v"(gp) : "memory");                       \
      bool ok = (d0.x!=SENT)&(d0.y!=SENT)&(d0.z!=SENT)&(d0.w!=SENT)         \
              & (d1.x!=SENT)&(d1.y!=SENT)&(d1.z!=SENT)&(d1.w!=SENT);        \
      if (ok || ++guard > 2000000L) break;                                  \
      if (guard > 2) __builtin_amdgcn_s_sleep(1);                           \
    }                                                                       \
    *(uint4*)&hsl[NB][sb][sws0] = d0;                                       \
    *(uint4*)&hsl[NB][sb][sws1] = d1;                                       \
  }

  STAGE(0, 0);
  __syncthreads();

  for (int s = 0; s < 512; s++) {
    int buf = s & 1;
    f4 a0 = (f4){0.f,0.f,0.f,0.f}, a1 = a0, a2 = a0;
#pragma unroll
    for (int ks = 0; ks < 16; ks++) {
      int g = ks*4 + kb;
      h8 hf = *(const h8*)&hsl[buf][b7][(g ^ b7) << 3];
      a0 = __builtin_amdgcn_mfma_f32_16x16x32_f16(wb[0][ks], hf, a0, 0, 0, 0);
      a1 = __builtin_amdgcn_mfma_f32_16x16x32_f16(wb[1][ks], hf, a1, 0, 0, 0);
      a2 = __builtin_amdgcn_mfma_f32_16x16x32_f16(wb[2][ks], hf, a2, 0, 0, 0);
    }
    int t = dir ? (511 - s) : s;
    __half2 xzl = *(__half2*)&xz2.x, xzh = *(__half2*)&xz2.y;
    __half2 xrl = *(__half2*)&xr2.x, xrh = *(__half2*)&xr2.y;
    __half2 xhl = *(__half2*)&xh2.x, xhh = *(__half2*)&xh2.y;
    float2 fz0 = __half22float2(xzl), fz1 = __half22float2(xzh);
    float2 fr0 = __half22float2(xrl), fr1 = __half22float2(xrh);
    float2 fh0 = __half22float2(xhl), fh1 = __half22float2(xhh);
    float xzf[4] = {fz0.x, fz0.y, fz1.x, fz1.y};
    float xrf[4] = {fr0.x, fr0.y, fr1.x, fr1.y};
    float xhf[4] = {fh0.x, fh0.y, fh1.x, fh1.y};
#pragma unroll
    for (int q = 0; q < 4; q++) {
      float az = (q==0? a0[0] : q==1? a0[1] : q==2? a0[2] : a0[3]);
      float ar = (q==0? a1[0] : q==1? a1[1] : q==2? a1[2] : a1[3]);
      float ah = (q==0? a2[0] : q==1? a2[1] : q==2? a2[2] : a2[3]);
      float z = 1.f/(1.f + __expf(-(xzf[q] + br3[0][q] + az)));
      float r = 1.f/(1.f + __expf(-(xrf[q] + br3[1][q] + ar)));
      float hh = fmaxf(xhf[q] + r*(br3[2][q] + ah), 0.f);
      hreg[q] = z*hreg[q] + (1.f - z)*hh;
    }
    int pn = (s + 1) & 3;
    if (bval) {
      __half2 p01 = __floats2half2_rn(hreg[0], hreg[1]);
      __half2 p23 = __floats2half2_rn(hreg[2], hreg[3]);
      unsigned pk0 = *(unsigned*)&p01, pk1 = *(unsigned*)&p23;
      unsigned long long pkl = ((unsigned long long)pk1 << 32) | pk0;
      (void)__hip_atomic_exchange(
          (unsigned long long*)&hbg[pn*2048 + wg*256 + b*32 + wv*8 + kb*2],
          pkl, __ATOMIC_RELAXED, __HIP_MEMORY_SCOPE_AGENT);
      uint2 pv; pv.x = pk0; pv.y = pk1;
      *(uint2*)((unsigned*)H + (size_t)((b0 + b)*TT + t)*512 + dir*256 + upair) = pv;
    }
    {
      int tn = (dir ? (510 - s) : (s + 1)) & 511;
      const unsigned* xp = (const unsigned*)xg + (size_t)((b0 + b7)*TT + tn)*768;
      xz2 = *(const uint2*)(xp + upair);
      xr2 = *(const uint2*)(xp + 256 + upair);
      xh2 = *(const uint2*)(xp + 512 + upair);
    }
    if (s < 511) STAGE(pn, buf ^ 1);
    if (tid < 128)
      (void)__hip_atomic_exchange(
          (unsigned long long*)&hbg[((s+3)&3)*2048 + wg*256] + tid,
          0xFFFFFFFFFFFFFFFFull, __ATOMIC_RELAXED, __HIP_MEMORY_SCOPE_AGENT);
    __syncthreads();   // vmcnt drain: publishes + resets flushed promptly
  }
#undef STAGE
}

// ---------------- row softmax over V=1024, in place ----------------
__global__ __launch_bounds__(256) void softmax_k(float* __restrict__ p) {
  size_t row = blockIdx.x;
  float* pr = p + row*VV;
  int tid = threadIdx.x;
  float4 v = ((float4*)pr)[tid];
  float m = fmaxf(fmaxf(v.x, v.y), fmaxf(v.z, v.w));
#pragma unroll
  for (int o = 32; o >= 1; o >>= 1) m = fmaxf(m, __shfl_xor(m, o));
  __shared__ float red[4];
  __shared__ float red2[4];
  int w = tid >> 6;
  if ((tid & 63) == 0) red[w] = m;
  __syncthreads();
  m = fmaxf(fmaxf(red[0], red[1]), fmaxf(red[2], red[3]));
  v.x = __expf(v.x - m); v.y = __expf(v.y - m);
  v.z = __expf(v.z - m); v.w = __expf(v.w - m);
  float s = v.x + v.y + v.z + v.w;
#pragma unroll
  for (int o = 32; o >= 1; o >>= 1) s += __shfl_xor(s, o);
  if ((tid & 63) == 0) red2[w] = s;
  __syncthreads();
  s = red2[0] + red2[1] + red2[2] + red2[3];
  float inv = 1.f / s;
  v.x *= inv; v.y *= inv; v.z *= inv; v.w *= inv;
  ((float4*)pr)[tid] = v;
}

extern "C" void kernel_launch(void* const* d_in, const int* in_sizes, int n_in,
                              void* d_out, int out_size, void* d_ws, size_t ws_size,
                              hipStream_t stream) {
  const float* x      = (const float*)d_in[0];
  const float* conv_w = (const float*)d_in[1];
  const float* conv_b = (const float*)d_in[2];
  const float* wx_f   = (const float*)d_in[3];
  const float* wh_f   = (const float*)d_in[4];
  const float* bi_f   = (const float*)d_in[5];
  const float* br_f   = (const float*)d_in[6];
  const float* wx_b   = (const float*)d_in[7];
  const float* wh_b   = (const float*)d_in[8];
  const float* bi_b   = (const float*)d_in[9];
  const float* br_b   = (const float*)d_in[10];
  const float* gam    = (const float*)d_in[11];
  const float* bet    = (const float*)d_in[12];
  const float* mu_    = (const float*)d_in[13];
  const float* var_   = (const float*)d_in[14];
  const float* dw     = (const float*)d_in[15];
  const float* db     = (const float*)d_in[16];

  char* ws = (char*)d_ws;
  __half* xgf   = (__half*)(ws + 0);
  __half* xgb   = (__half*)(ws + 50331648LL);
  __half* WxfT2 = (__half*)(ws + 100663296LL);
  __half* WxbT2 = (__half*)(ws + 103809024LL);
  __half* DwT2  = (__half*)(ws + 106954752LL);
  float*  bias2 = (float*)(ws + 109051904LL);
  __half* c0    = (__half*)(ws + 109056000LL);
  __half* H     = (__half*)(ws + 109056000LL);   // overlays c0 (c0 dead before H written)
  unsigned* hb1 = (unsigned*)(ws + 142610432LL); // 256 KB (layer 1 exchange)
  unsigned* hb2 = (unsigned*)(ws + 142872576LL); // 256 KB (layer 2 exchange)
  if (ws_size < 143134720ULL) return;
  float* logits = (float*)d_out;

  // sentinel-fill both layers' exchange buffers (0xFF bytes = f16 NaN pairs)
  (void)hipMemsetAsync(hb1, 0xFF, 524288, stream);

  prep_wx_k<<<dim3(8,24,2), 256, 0, stream>>>(wx_f, wx_b, WxfT2, WxbT2);
  prep_dense_k<<<dim3(8,16), 256, 0, stream>>>(dw, gam, var_, DwT2);
  prep_bias_k<<<4, 256, 0, stream>>>(dw, db, gam, bet, mu_, var_, bias2);

  conv_bn_k<<<dim3(32,32,2), 256, 0, stream>>>(x, conv_w, conv_b, gam, bet, mu_, var_, c0);

  // layer-1 xg: fwd+bwd fused into one launch (shared A = c0)
  hgemm2_k<1><<<dim3(24,128), 256, 0, stream>>>(c0, WxfT2, WxbT2, bi_f, bi_b,
                                                xgf, xgb, MM, GG, 512, 512);
  gru_layer_k<<<64, 256, 0, stream>>>(xgf, xgb, wh_f, wh_b, br_f, br_b, H, hb1);
  // layer-2 xg: fwd+bwd fused (shared A = H, K=1024)
  hgemm2_k<1><<<dim3(24,128), 256, 0, stream>>>(H, WxfT2, WxbT2, bi_f, bi_b,
                                                xgf, xgb, MM, GG, 1024, 1024);
  gru_layer_k<<<64, 256, 0, stream>>>(xgf, xgb, wh_f, wh_b, br_f, br_b, H, hb2);
  hgemm2_k<0><<<dim3(8,128), 256, 0, stream>>>(H, DwT2, nullptr, bias2, nullptr,
                                               logits, nullptr, MM, VV, 1024, 1024);
  softmax_k<<<MM, 256, 0, stream>>>(logits);
}